// Round 8
// baseline (393.206 us; speedup 1.0000x reference)
//
#include <hip/hip_runtime.h>
#include <hip/hip_bf16.h>
#include <cstdint>

typedef __hip_bfloat16 bf16;
typedef __attribute__((ext_vector_type(8))) short bfrag;   // 8 bf16 (4 VGPRs)
typedef __attribute__((ext_vector_type(4))) float facc;    // 4 fp32 acc

#define B_    16384
#define D_    1024
#define DOUT_ 1024
#define R_    8
#define DH_   512
#define RH_   4096

#define BM 256
#define BN 256
#define BK 64

#define NXCD 8

#define AS1(p) ((const __attribute__((address_space(1))) void*)(p))
#define AS3(p) ((__attribute__((address_space(3))) void*)(p))

// inline-asm ds_read_b128 (fixed issue order; lgkm counted against these only).
#define DSR(dst, addr, off) \
    asm volatile("ds_read_b128 %0, %1 offset:%c2" : "=v"(dst) : "v"(addr), "i"(off))
#define LGKM(n) do { asm volatile("s_waitcnt lgkmcnt(" #n ")" ::: "memory"); \
                     __builtin_amdgcn_sched_barrier(0); } while (0)

static __device__ __forceinline__ uint32_t pack2bf(float a, float b) {
    unsigned short ua = __builtin_bit_cast(unsigned short, __float2bfloat16(a));
    unsigned short ub = __builtin_bit_cast(unsigned short, __float2bfloat16(b));
    return (uint32_t)ua | ((uint32_t)ub << 16);
}

// ---------------- fp32 -> bf16 conversion (vectorized) ----------------
__global__ void k_cvt(const float* __restrict__ in, bf16* __restrict__ out, long n)
{
    long i = ((long)blockIdx.x * blockDim.x + threadIdx.x) * 4;
    if (i >= n) return;
    float4 v = *reinterpret_cast<const float4*>(in + i);
    uint2 o;
    o.x = pack2bf(v.x, v.y);
    o.y = pack2bf(v.z, v.w);
    *reinterpret_cast<uint2*>(out + i) = o;
}

// ---- W2 (R,DOUT,DH) -> B4 (DOUT, R*DH) with B4[o][r*DH+h] = W2[r][o][h] ----
__global__ void k_cvt_w2(const float* __restrict__ W2, bf16* __restrict__ out)
{
    int b = blockIdx.x;            // 0 .. R_*DOUT_-1
    int r = b >> 10;               // DOUT_ = 1024
    int o = b & 1023;
    const float4* src = reinterpret_cast<const float4*>(W2 + ((long)r * DOUT_ + o) * DH_);
    bf16* dst = out + (long)o * RH_ + r * DH_;
    int t = threadIdx.x;           // 0..127, covers 512 floats
    float4 v = src[t];
    uint2 p;
    p.x = pack2bf(v.x, v.y);
    p.y = pack2bf(v.z, v.w);
    *reinterpret_cast<uint2*>(dst + t * 4) = p;
}

// ---------------- gate = softmax(x @ Wg.T + bg) ----------------
__global__ __launch_bounds__(256) void k_gate(const float* __restrict__ x,
                                              const float* __restrict__ Wg,
                                              const float* __restrict__ bg,
                                              float* __restrict__ gate)
{
    __shared__ float sWg[R_ * D_];
    __shared__ float sbg[R_];
    for (int i = threadIdx.x; i < R_ * D_ / 4; i += 256)
        reinterpret_cast<float4*>(sWg)[i] = reinterpret_cast<const float4*>(Wg)[i];
    if (threadIdx.x < R_) sbg[threadIdx.x] = bg[threadIdx.x];
    __syncthreads();

    const int lane = threadIdx.x & 63;
    const int wave = threadIdx.x >> 6;
    const int row  = blockIdx.x * 4 + wave;     // grid = B_/4

    const float4* xr = reinterpret_cast<const float4*>(x + (long)row * D_);
    float s[R_] = {};
    #pragma unroll
    for (int c = 0; c < 4; ++c) {
        float4 xv = xr[lane + c * 64];
        #pragma unroll
        for (int r = 0; r < R_; ++r) {
            float4 wv = reinterpret_cast<const float4*>(sWg + r * D_)[lane + c * 64];
            s[r] += xv.x * wv.x + xv.y * wv.y + xv.z * wv.z + xv.w * wv.w;
        }
    }
    #pragma unroll
    for (int r = 0; r < R_; ++r) {
        float v = s[r];
        #pragma unroll
        for (int off = 32; off > 0; off >>= 1) v += __shfl_xor(v, off);
        s[r] = v + sbg[r];
    }
    float m = s[0];
    #pragma unroll
    for (int r = 1; r < R_; ++r) m = fmaxf(m, s[r]);
    float den = 0.f;
    #pragma unroll
    for (int r = 0; r < R_; ++r) { s[r] = __expf(s[r] - m); den += s[r]; }
    float inv = 1.f / den;
    if (lane < R_) gate[(long)row * R_ + lane] = s[lane] * inv;
}

// ======== 256x256 8-phase bf16 MFMA GEMM (read-ahead + counted lgkm) ========
// EPI 0: C(bf16) = dot + bias[col]
// EPI 1: C(bf16) = relu(dot + bias[col]) * gate[row][col>>9]
// EPI 2: C(f32)  = dot + sum_r gate[row][r]*b2[r][col]
//
// Quadrants: Q0(Alo,Blo) Q1(Alo,Bhi) Q2(Ahi,Bhi) Q3(Ahi,Blo).
// Reads for phase p issued at END of phase p-1 in FIXED order; phase p's MFMA
// cluster uses counted lgkmcnt so MFMAs start as fragments land and the LDS
// queue drains DURING the cluster. Staging 1 half-tile/phase; vmcnt(4)/tile.
//
// Grid decode is COLUMN-MAJOR under the bijective XCD chunking: each XCD owns
// a contiguous column band -> its B-slice (<=4MB) stays L2-resident (the r8
// change; row-major decode gave every XCD the full 8MB B = guaranteed thrash).
#define MFMA_BF16 __builtin_amdgcn_mfma_f32_16x16x32_bf16

template <int EPI>
__global__ __launch_bounds__(512, 2)
void k_gemm(const bf16* __restrict__ A, const bf16* __restrict__ Bm,
            const float* __restrict__ bias, const float* __restrict__ gate,
            const float* __restrict__ b2v, void* __restrict__ Cout,
            int M, int N, int K, int gate_row0)
{
    __shared__ char lds[131072];

    const int tid  = threadIdx.x;
    const int lane = tid & 63;
    const int wave = tid >> 6;
    const int wr   = wave >> 2;       // 0..1
    const int wc   = wave & 3;        // 0..3

    // ---- XCD-aware bijective chunked swizzle (m204) + column-major decode ----
    const int nwg  = gridDim.x * gridDim.y;
    const int orig = blockIdx.y * gridDim.x + blockIdx.x;
    const int xcd  = orig % NXCD;
    const int q    = nwg / NXCD;
    const int rr   = nwg % NXCD;
    const int wgid = (xcd < rr ? xcd * (q + 1) : rr * (q + 1) + (xcd - rr) * q)
                   + orig / NXCD;
    const int bn0  = (wgid / gridDim.y) * BN;   // column-major: XCD = column band
    const int bm0  = (wgid % gridDim.y) * BM;

    const int lrow = lane & 15;
    const int kgrp = lane >> 4;

    // ---- staging: per-thread pre-swizzled source column, linear LDS dest ----
    const int s_colb  = ((tid & 7) * 16) ^ (((tid >> 3) & 7) << 4);
    const int s_row   = tid >> 3;          // 0..63
    const int lds_off = tid * 16;

    const long Kb   = (long)K * 2;         // row stride in bytes
    const long r64  = 64 * Kb;
    const long r128 = 128 * Kb;
    const char* gA0 = (const char*)A  + (long)(bm0 + s_row) * Kb + s_colb;
    const char* gB0 = (const char*)Bm + (long)(bn0 + s_row) * Kb + s_colb;

    auto stageH = [&](int buf, int h, long kb) {
        char* ldst = lds + buf * 65536
                   + (h < 2 ? h * 16384 : 32768 + (h - 2) * 16384) + lds_off;
        const char* g = (h < 2 ? gA0 + h * r128 : gB0 + (h - 2) * r128) + kb;
        __builtin_amdgcn_global_load_lds(AS1(g),       AS3(ldst),        16, 0, 0);
        __builtin_amdgcn_global_load_lds(AS1(g + r64), AS3(ldst + 8192), 16, 0, 0);
    };

    // ---- ds_read addressing (swizzled column), per-buffer address registers ----
    const int swzk  = (lrow & 7) << 4;
    const int colK0 = (kgrp * 16) ^ swzk;            // kk=0
    const int colK1 = (kgrp * 16 + 64) ^ swzk;       // kk=1
    const uint32_t ldsbase = (uint32_t)(uintptr_t)AS3(lds);
    const uint32_t aA00 = ldsbase + (wr * 128 + lrow) * 128 + colK0;
    const uint32_t aA01 = ldsbase + (wr * 128 + lrow) * 128 + colK1;
    const uint32_t aB00 = ldsbase + 32768 + (wc * 64 + lrow) * 128 + colK0;
    const uint32_t aB01 = ldsbase + 32768 + (wc * 64 + lrow) * 128 + colK1;
    const uint32_t aA10 = aA00 + 65536, aA11 = aA01 + 65536;
    const uint32_t aB10 = aB00 + 65536, aB11 = aB01 + 65536;

    facc acc[8][4];
    #pragma unroll
    for (int m = 0; m < 8; ++m)
        #pragma unroll
        for (int n = 0; n < 4; ++n)
            acc[m][n] = facc{0.f, 0.f, 0.f, 0.f};

    const int NT = K / BK;   // 16 or 64 (even)

    bfrag aF[4][2];          // A-lo then A-hi (time-shared)
    bfrag bHi[2][2];         // B-hi of current tile
    bfrag bLoE[2][2];        // B-lo, even tiles
    bfrag bLoO[2][2];        // B-lo, odd tiles

    // canonical Q0 read order: bLo[0][0], bLo[0][1], bLo[1][0], bLo[1][1],
    // then aF[m][0], aF[m][1] for m=0..3  (12 reads)
    auto rdQ0 = [&](bfrag (&bLo)[2][2], uint32_t A0, uint32_t A1,
                    uint32_t B0, uint32_t B1) {
        DSR(bLo[0][0], B0, 0);    DSR(bLo[0][1], B1, 0);
        DSR(bLo[1][0], B0, 2048); DSR(bLo[1][1], B1, 2048);
        #pragma unroll
        for (int m = 0; m < 4; ++m) {
            DSR(aF[m][0], A0, m * 2048);
            DSR(aF[m][1], A1, m * 2048);
        }
    };

    // ---- prologue: stage tile0 (H0-H3) + tile1 (H0,H1); preload Q0 frags ----
    stageH(0, 0, 0); stageH(0, 1, 0); stageH(0, 2, 0); stageH(0, 3, 0);
    stageH(1, 0, 128); stageH(1, 1, 128);
    asm volatile("s_waitcnt vmcnt(4)" ::: "memory");
    __builtin_amdgcn_s_barrier();
    rdQ0(bLoE, aA00, aA01, aB00, aB01);

    auto ktile = [&](int t, int curbuf,
                     uint32_t A0c, uint32_t A1c, uint32_t B0c, uint32_t B1c,
                     uint32_t A0n, uint32_t A1n, uint32_t B0n, uint32_t B1n,
                     bfrag (&bLoC)[2][2], bfrag (&bLoN)[2][2]) {
        const long k1b = (long)(t + 1) * 128;
        const long k2b = (long)(t + 2) * 128;
        const int  nb  = curbuf ^ 1;

        // ===== P0: Q0 = Alo x Blo  (12 outstanding: bLo4 + aLo8) =====
        if (t + 1 < NT) stageH(nb, 2, k1b);
        __builtin_amdgcn_s_barrier();
        __builtin_amdgcn_s_setprio(1);
        LGKM(6);
        acc[0][0] = MFMA_BF16(aF[0][0], bLoC[0][0], acc[0][0], 0, 0, 0);
        acc[0][0] = MFMA_BF16(aF[0][1], bLoC[0][1], acc[0][0], 0, 0, 0);
        acc[0][1] = MFMA_BF16(aF[0][0], bLoC[1][0], acc[0][1], 0, 0, 0);
        acc[0][1] = MFMA_BF16(aF[0][1], bLoC[1][1], acc[0][1], 0, 0, 0);
        LGKM(4);
        acc[1][0] = MFMA_BF16(aF[1][0], bLoC[0][0], acc[1][0], 0, 0, 0);
        acc[1][0] = MFMA_BF16(aF[1][1], bLoC[0][1], acc[1][0], 0, 0, 0);
        acc[1][1] = MFMA_BF16(aF[1][0], bLoC[1][0], acc[1][1], 0, 0, 0);
        acc[1][1] = MFMA_BF16(aF[1][1], bLoC[1][1], acc[1][1], 0, 0, 0);
        LGKM(2);
        acc[2][0] = MFMA_BF16(aF[2][0], bLoC[0][0], acc[2][0], 0, 0, 0);
        acc[2][0] = MFMA_BF16(aF[2][1], bLoC[0][1], acc[2][0], 0, 0, 0);
        acc[2][1] = MFMA_BF16(aF[2][0], bLoC[1][0], acc[2][1], 0, 0, 0);
        acc[2][1] = MFMA_BF16(aF[2][1], bLoC[1][1], acc[2][1], 0, 0, 0);
        LGKM(0);
        acc[3][0] = MFMA_BF16(aF[3][0], bLoC[0][0], acc[3][0], 0, 0, 0);
        acc[3][0] = MFMA_BF16(aF[3][1], bLoC[0][1], acc[3][0], 0, 0, 0);
        acc[3][1] = MFMA_BF16(aF[3][0], bLoC[1][0], acc[3][1], 0, 0, 0);
        acc[3][1] = MFMA_BF16(aF[3][1], bLoC[1][1], acc[3][1], 0, 0, 0);
        __builtin_amdgcn_s_setprio(0);
        DSR(bHi[0][0], B0c, 2 * 2048); DSR(bHi[0][1], B1c, 2 * 2048);
        DSR(bHi[1][0], B0c, 3 * 2048); DSR(bHi[1][1], B1c, 3 * 2048);
        __builtin_amdgcn_s_barrier();

        // ===== P1: Q1 = Alo x Bhi  (4 outstanding: bHi) =====
        if (t + 1 < NT) stageH(nb, 3, k1b);
        __builtin_amdgcn_s_barrier();
        __builtin_amdgcn_s_setprio(1);
        LGKM(2);
        #pragma unroll
        for (int m = 0; m < 4; ++m) {
            acc[m][2] = MFMA_BF16(aF[m][0], bHi[0][0], acc[m][2], 0, 0, 0);
            acc[m][2] = MFMA_BF16(aF[m][1], bHi[0][1], acc[m][2], 0, 0, 0);
        }
        LGKM(0);
        #pragma unroll
        for (int m = 0; m < 4; ++m) {
            acc[m][3] = MFMA_BF16(aF[m][0], bHi[1][0], acc[m][3], 0, 0, 0);
            acc[m][3] = MFMA_BF16(aF[m][1], bHi[1][1], acc[m][3], 0, 0, 0);
        }
        __builtin_amdgcn_s_setprio(0);
        #pragma unroll
        for (int m = 0; m < 4; ++m) {
            DSR(aF[m][0], A0c, (4 + m) * 2048);
            DSR(aF[m][1], A1c, (4 + m) * 2048);
        }
        __builtin_amdgcn_s_barrier();

        // ===== P2: Q2 = Ahi x Bhi  (8 outstanding: aHi) =====
        if (t + 2 < NT) stageH(curbuf, 0, k2b);
        __builtin_amdgcn_s_barrier();
        __builtin_amdgcn_s_setprio(1);
        LGKM(6);
        acc[4][2] = MFMA_BF16(aF[0][0], bHi[0][0], acc[4][2], 0, 0, 0);
        acc[4][2] = MFMA_BF16(aF[0][1], bHi[0][1], acc[4][2], 0, 0, 0);
        acc[4][3] = MFMA_BF16(aF[0][0], bHi[1][0], acc[4][3], 0, 0, 0);
        acc[4][3] = MFMA_BF16(aF[0][1], bHi[1][1], acc[4][3], 0, 0, 0);
        LGKM(4);
        acc[5][2] = MFMA_BF16(aF[1][0], bHi[0][0], acc[5][2], 0, 0, 0);
        acc[5][2] = MFMA_BF16(aF[1][1], bHi[0][1], acc[5][2], 0, 0, 0);
        acc[5][3] = MFMA_BF16(aF[1][0], bHi[1][0], acc[5][3], 0, 0, 0);
        acc[5][3] = MFMA_BF16(aF[1][1], bHi[1][1], acc[5][3], 0, 0, 0);
        LGKM(2);
        acc[6][2] = MFMA_BF16(aF[2][0], bHi[0][0], acc[6][2], 0, 0, 0);
        acc[6][2] = MFMA_BF16(aF[2][1], bHi[0][1], acc[6][2], 0, 0, 0);
        acc[6][3] = MFMA_BF16(aF[2][0], bHi[1][0], acc[6][3], 0, 0, 0);
        acc[6][3] = MFMA_BF16(aF[2][1], bHi[1][1], acc[6][3], 0, 0, 0);
        LGKM(0);
        acc[7][2] = MFMA_BF16(aF[3][0], bHi[0][0], acc[7][2], 0, 0, 0);
        acc[7][2] = MFMA_BF16(aF[3][1], bHi[0][1], acc[7][2], 0, 0, 0);
        acc[7][3] = MFMA_BF16(aF[3][0], bHi[1][0], acc[7][3], 0, 0, 0);
        acc[7][3] = MFMA_BF16(aF[3][1], bHi[1][1], acc[7][3], 0, 0, 0);
        __builtin_amdgcn_s_setprio(0);
        __builtin_amdgcn_s_barrier();

        // ===== P3: Q3 = Ahi x Blo  (0 outstanding: no lgkm waits) =====
        if (t + 2 < NT) {
            stageH(curbuf, 1, k2b);
            asm volatile("s_waitcnt vmcnt(4)" ::: "memory");
        } else if (t + 1 < NT) {
            asm volatile("s_waitcnt vmcnt(0)" ::: "memory");
        }
        __builtin_amdgcn_s_barrier();
        __builtin_amdgcn_s_setprio(1);
        #pragma unroll
        for (int m = 0; m < 4; ++m) {
            acc[4 + m][0] = MFMA_BF16(aF[m][0], bLoC[0][0], acc[4 + m][0], 0, 0, 0);
            acc[4 + m][0] = MFMA_BF16(aF[m][1], bLoC[0][1], acc[4 + m][0], 0, 0, 0);
            acc[4 + m][1] = MFMA_BF16(aF[m][0], bLoC[1][0], acc[4 + m][1], 0, 0, 0);
            acc[4 + m][1] = MFMA_BF16(aF[m][1], bLoC[1][1], acc[4 + m][1], 0, 0, 0);
        }
        __builtin_amdgcn_s_setprio(0);
        if (t + 1 < NT) rdQ0(bLoN, A0n, A1n, B0n, B1n);
        __builtin_amdgcn_s_barrier();
    };

    for (int t = 0; t < NT; t += 2) {
        ktile(t,     0, aA00, aA01, aB00, aB01, aA10, aA11, aB10, aB11, bLoE, bLoO);
        ktile(t + 1, 1, aA10, aA11, aB10, aB11, aA00, aA01, aB00, aB01, bLoO, bLoE);
    }

    // ---------------- epilogue ----------------
    if constexpr (EPI == 2) {
        float* Cf = reinterpret_cast<float*>(Cout);
        float b2c[4][R_];
        #pragma unroll
        for (int n = 0; n < 4; ++n) {
            const int col = bn0 + wc * 64 + n * 16 + lrow;
            #pragma unroll
            for (int r = 0; r < R_; ++r) b2c[n][r] = b2v[r * N + col];
        }
        #pragma unroll
        for (int m = 0; m < 8; ++m) {
            #pragma unroll
            for (int j = 0; j < 4; ++j) {
                const int row = bm0 + wr * 128 + m * 16 + kgrp * 4 + j;
                const float* g = gate + (long)(gate_row0 + row) * R_;
                float gv[R_];
                #pragma unroll
                for (int r = 0; r < R_; ++r) gv[r] = g[r];
                #pragma unroll
                for (int n = 0; n < 4; ++n) {
                    const int col = bn0 + wc * 64 + n * 16 + lrow;
                    float sv = acc[m][n][j];
                    #pragma unroll
                    for (int r = 0; r < R_; ++r) sv += gv[r] * b2c[n][r];
                    Cf[(long)row * N + col] = sv;
                }
            }
        }
    } else {
        bf16* Cb = reinterpret_cast<bf16*>(Cout);
        float bcol[4];
        #pragma unroll
        for (int n = 0; n < 4; ++n) bcol[n] = bias[bn0 + wc * 64 + n * 16 + lrow];
        #pragma unroll
        for (int m = 0; m < 8; ++m) {
            #pragma unroll
            for (int j = 0; j < 4; ++j) {
                const int row = bm0 + wr * 128 + m * 16 + kgrp * 4 + j;
                float gv[4];
                if constexpr (EPI == 1) {
                    #pragma unroll
                    for (int n = 0; n < 4; ++n) {
                        const int col = bn0 + wc * 64 + n * 16 + lrow;
                        gv[n] = gate[(long)(gate_row0 + row) * R_ + (col >> 9)];
                    }
                }
                #pragma unroll
                for (int n = 0; n < 4; ++n) {
                    const int col = bn0 + wc * 64 + n * 16 + lrow;
                    float v = acc[m][n][j] + bcol[n];
                    if constexpr (EPI == 1) v = fmaxf(v, 0.f) * gv[n];
                    Cb[(long)row * N + col] = __float2bfloat16(v);
                }
            }
        }
    }
}

extern "C" void kernel_launch(void* const* d_in, const int* in_sizes, int n_in,
                              void* d_out, int out_size, void* d_ws, size_t ws_size,
                              hipStream_t stream)
{
    const float* x   = (const float*)d_in[0];
    const float* ipw = (const float*)d_in[1];
    const float* ipb = (const float*)d_in[2];
    const float* opw = (const float*)d_in[3];
    const float* opb = (const float*)d_in[4];
    const float* W1  = (const float*)d_in[5];
    const float* b1  = (const float*)d_in[6];
    const float* W2  = (const float*)d_in[7];
    const float* b2  = (const float*)d_in[8];
    const float* Wg  = (const float*)d_in[9];
    const float* bg  = (const float*)d_in[10];
    float* out = (float*)d_out;

    char* ws = (char*)d_ws;
    size_t off = 0;
    auto alloc = [&](size_t bytes) -> void* {
        void* p = ws + off;
        off += (bytes + 255) & ~(size_t)255;
        return p;
    };

    bf16* xb   = (bf16*)alloc((size_t)B_ * D_ * 2);     // x in bf16
    bf16* vb   = (bf16*)alloc((size_t)B_ * D_ * 2);     // v
    bf16* Wvb  = (bf16*)alloc((size_t)D_ * D_ * 2);
    bf16* Wob  = (bf16*)alloc((size_t)D_ * D_ * 2);
    bf16* W1b  = (bf16*)alloc((size_t)RH_ * D_ * 2);
    bf16* W2b  = (bf16*)alloc((size_t)DOUT_ * RH_ * 2);
    float* gate = (float*)alloc((size_t)B_ * R_ * 4);

    // h' chunk buffer: largest M-chunk that fits the workspace (multiple of 256)
    int mc = B_;
    while (off + (size_t)mc * RH_ * 2 > ws_size && mc > 1024) mc >>= 1;
    bf16* hb = (bf16*)alloc((size_t)mc * RH_ * 2);
    bf16* ab = xb;   // attended reuses xb (xb is dead after G1; gate reads fp32 x)

    // ---- conversions ----
    k_cvt<<<(B_ * D_) / 1024, 256, 0, stream>>>(x, xb, (long)B_ * D_);
    k_cvt<<<(D_ * D_) / 1024, 256, 0, stream>>>(ipw + (size_t)2 * D_ * D_, Wvb, (long)D_ * D_);
    k_cvt<<<(D_ * D_) / 1024, 256, 0, stream>>>(opw, Wob, (long)D_ * D_);
    k_cvt<<<(RH_ * D_) / 1024, 256, 0, stream>>>(W1, W1b, (long)RH_ * D_);
    k_cvt_w2<<<R_ * DOUT_, 128, 0, stream>>>(W2, W2b);

    // ---- gate (reads fp32 x directly) ----
    k_gate<<<B_ / 4, 256, 0, stream>>>(x, Wg, bg, gate);

    // ---- G1: v = x @ Wv^T + bv ----
    k_gemm<0><<<dim3(D_ / BN, B_ / BM), 512, 0, stream>>>(
        xb, Wvb, ipb + 2 * D_, nullptr, nullptr, vb, B_, D_, D_, 0);

    // ---- G2: attended = v @ Wout^T + bout ----
    k_gemm<0><<<dim3(D_ / BN, B_ / BM), 512, 0, stream>>>(
        vb, Wob, opb, nullptr, nullptr, ab, B_, D_, D_, 0);

    // ---- G3 + G4, chunked over M ----
    for (int m0 = 0; m0 < B_; m0 += mc) {
        // h' = relu(att @ W1cat^T + b1) * gate[:, r]
        k_gemm<1><<<dim3(RH_ / BN, mc / BM), 512, 0, stream>>>(
            ab + (size_t)m0 * D_, W1b, b1, gate, nullptr, hb, mc, RH_, D_, m0);
        // out = h' @ W2cat + gate @ b2
        k_gemm<2><<<dim3(DOUT_ / BN, mc / BM), 512, 0, stream>>>(
            hb, W2b, nullptr, gate, b2, out + (size_t)m0 * DOUT_, mc, DOUT_, RH_, m0);
    }
}

// Round 9
// 381.798 us; speedup vs baseline: 1.0299x; 1.0299x over previous
//
#include <hip/hip_runtime.h>
#include <hip/hip_bf16.h>
#include <cstdint>

typedef __hip_bfloat16 bf16;
typedef __attribute__((ext_vector_type(8))) short bfrag;   // 8 bf16 (4 VGPRs)
typedef __attribute__((ext_vector_type(4))) float facc;    // 4 fp32 acc

#define B_    16384
#define D_    1024
#define DOUT_ 1024
#define R_    8
#define DH_   512
#define RH_   4096

#define BM 256
#define BN 256
#define BK 64

#define NXCD 8

#define AS1(p) ((const __attribute__((address_space(1))) void*)(p))
#define AS3(p) ((__attribute__((address_space(3))) void*)(p))

// inline-asm ds_read_b128 (fixed issue order; lgkm counted against these only).
#define DSR(dst, addr, off) \
    asm volatile("ds_read_b128 %0, %1 offset:%c2" : "=v"(dst) : "v"(addr), "i"(off))
#define LGKM(n) do { asm volatile("s_waitcnt lgkmcnt(" #n ")" ::: "memory"); \
                     __builtin_amdgcn_sched_barrier(0); } while (0)

static __device__ __forceinline__ uint32_t pack2bf(float a, float b) {
    unsigned short ua = __builtin_bit_cast(unsigned short, __float2bfloat16(a));
    unsigned short ub = __builtin_bit_cast(unsigned short, __float2bfloat16(b));
    return (uint32_t)ua | ((uint32_t)ub << 16);
}

// ---------------- fp32 -> bf16 conversion (vectorized) ----------------
__global__ void k_cvt(const float* __restrict__ in, bf16* __restrict__ out, long n)
{
    long i = ((long)blockIdx.x * blockDim.x + threadIdx.x) * 4;
    if (i >= n) return;
    float4 v = *reinterpret_cast<const float4*>(in + i);
    uint2 o;
    o.x = pack2bf(v.x, v.y);
    o.y = pack2bf(v.z, v.w);
    *reinterpret_cast<uint2*>(out + i) = o;
}

// ---- W2 (R,DOUT,DH) -> B4 (DOUT, R*DH) with B4[o][r*DH+h] = W2[r][o][h] ----
__global__ void k_cvt_w2(const float* __restrict__ W2, bf16* __restrict__ out)
{
    int b = blockIdx.x;            // 0 .. R_*DOUT_-1
    int r = b >> 10;               // DOUT_ = 1024
    int o = b & 1023;
    const float4* src = reinterpret_cast<const float4*>(W2 + ((long)r * DOUT_ + o) * DH_);
    bf16* dst = out + (long)o * RH_ + r * DH_;
    int t = threadIdx.x;           // 0..127, covers 512 floats
    float4 v = src[t];
    uint2 p;
    p.x = pack2bf(v.x, v.y);
    p.y = pack2bf(v.z, v.w);
    *reinterpret_cast<uint2*>(dst + t * 4) = p;
}

// ---- Wv (1024x1024 f32, [j][d]) -> WvT bf16 [d][j] (LDS-tiled transpose) ----
__global__ __launch_bounds__(256) void k_cvt_wvT(const float* __restrict__ Wv,
                                                 bf16* __restrict__ outT)
{
    __shared__ float tile[64][65];
    const int j0 = blockIdx.y * 64;   // source row block
    const int d0 = blockIdx.x * 64;   // source col block
    const int tx = threadIdx.x & 15;  // 16 x float4 = 64 cols
    const int ty = threadIdx.x >> 4;  // 16 rows per pass
    #pragma unroll
    for (int p = 0; p < 4; ++p) {
        int r = p * 16 + ty;
        float4 v = *reinterpret_cast<const float4*>(&Wv[(long)(j0 + r) * D_ + d0 + tx * 4]);
        tile[r][tx * 4 + 0] = v.x; tile[r][tx * 4 + 1] = v.y;
        tile[r][tx * 4 + 2] = v.z; tile[r][tx * 4 + 3] = v.w;
    }
    __syncthreads();
    #pragma unroll
    for (int p = 0; p < 4; ++p) {
        int r = p * 16 + ty;          // output row (d index)
        uint2 o;
        o.x = pack2bf(tile[tx * 4 + 0][r], tile[tx * 4 + 1][r]);
        o.y = pack2bf(tile[tx * 4 + 2][r], tile[tx * 4 + 3][r]);
        *reinterpret_cast<uint2*>(&outT[(long)(d0 + r) * D_ + j0 + tx * 4]) = o;
    }
}

// ---- beff[o] = sum_d Wout[o,d]*bv[d] + bout[o] ----
__global__ __launch_bounds__(256) void k_beff(const float* __restrict__ Wout,
                                              const float* __restrict__ bv,
                                              const float* __restrict__ bout,
                                              float* __restrict__ beff)
{
    const int o = blockIdx.x;
    float s = 0.f;
    for (int d = threadIdx.x; d < D_; d += 256)
        s += Wout[(long)o * D_ + d] * bv[d];
    #pragma unroll
    for (int off = 32; off > 0; off >>= 1) s += __shfl_xor(s, off);
    __shared__ float ps[4];
    if ((threadIdx.x & 63) == 0) ps[threadIdx.x >> 6] = s;
    __syncthreads();
    if (threadIdx.x == 0)
        beff[o] = ps[0] + ps[1] + ps[2] + ps[3] + bout[o];
}

// ---------------- gate = softmax(x @ Wg.T + bg) ----------------
__global__ __launch_bounds__(256) void k_gate(const float* __restrict__ x,
                                              const float* __restrict__ Wg,
                                              const float* __restrict__ bg,
                                              float* __restrict__ gate)
{
    __shared__ float sWg[R_ * D_];
    __shared__ float sbg[R_];
    for (int i = threadIdx.x; i < R_ * D_ / 4; i += 256)
        reinterpret_cast<float4*>(sWg)[i] = reinterpret_cast<const float4*>(Wg)[i];
    if (threadIdx.x < R_) sbg[threadIdx.x] = bg[threadIdx.x];
    __syncthreads();

    const int lane = threadIdx.x & 63;
    const int wave = threadIdx.x >> 6;
    const int row  = blockIdx.x * 4 + wave;     // grid = B_/4

    const float4* xr = reinterpret_cast<const float4*>(x + (long)row * D_);
    float s[R_] = {};
    #pragma unroll
    for (int c = 0; c < 4; ++c) {
        float4 xv = xr[lane + c * 64];
        #pragma unroll
        for (int r = 0; r < R_; ++r) {
            float4 wv = reinterpret_cast<const float4*>(sWg + r * D_)[lane + c * 64];
            s[r] += xv.x * wv.x + xv.y * wv.y + xv.z * wv.z + xv.w * wv.w;
        }
    }
    #pragma unroll
    for (int r = 0; r < R_; ++r) {
        float v = s[r];
        #pragma unroll
        for (int off = 32; off > 0; off >>= 1) v += __shfl_xor(v, off);
        s[r] = v + sbg[r];
    }
    float m = s[0];
    #pragma unroll
    for (int r = 1; r < R_; ++r) m = fmaxf(m, s[r]);
    float den = 0.f;
    #pragma unroll
    for (int r = 0; r < R_; ++r) { s[r] = __expf(s[r] - m); den += s[r]; }
    float inv = 1.f / den;
    if (lane < R_) gate[(long)row * R_ + lane] = s[lane] * inv;
}

// ======== 256x256 8-phase bf16 MFMA GEMM (read-ahead + counted lgkm) ========
// EPI 0: C(bf16) = dot + bias[col]
// EPI 1: C(bf16) = relu(dot + bias[col]) * gate[row][col>>9]
// EPI 2: C(f32)  = dot + sum_r gate[row][r]*b2[r][col]
// EPI 3: C(bf16) = dot                  (plain; for Weff = Wout@Wv)
#define MFMA_BF16 __builtin_amdgcn_mfma_f32_16x16x32_bf16

template <int EPI>
__global__ __launch_bounds__(512, 2)
void k_gemm(const bf16* __restrict__ A, const bf16* __restrict__ Bm,
            const float* __restrict__ bias, const float* __restrict__ gate,
            const float* __restrict__ b2v, void* __restrict__ Cout,
            int M, int N, int K, int gate_row0)
{
    __shared__ char lds[131072];

    const int tid  = threadIdx.x;
    const int lane = tid & 63;
    const int wave = tid >> 6;
    const int wr   = wave >> 2;       // 0..1
    const int wc   = wave & 3;        // 0..3

    // ---- XCD-aware bijective chunked swizzle (m204), row-major decode (r6) ----
    const int nwg  = gridDim.x * gridDim.y;
    const int orig = blockIdx.y * gridDim.x + blockIdx.x;
    const int xcd  = orig % NXCD;
    const int q    = nwg / NXCD;
    const int rr   = nwg % NXCD;
    const int wgid = (xcd < rr ? xcd * (q + 1) : rr * (q + 1) + (xcd - rr) * q)
                   + orig / NXCD;
    const int bn0  = (wgid % gridDim.x) * BN;
    const int bm0  = (wgid / gridDim.x) * BM;

    const int lrow = lane & 15;
    const int kgrp = lane >> 4;

    // ---- staging: per-thread pre-swizzled source column, linear LDS dest ----
    const int s_colb  = ((tid & 7) * 16) ^ (((tid >> 3) & 7) << 4);
    const int s_row   = tid >> 3;          // 0..63
    const int lds_off = tid * 16;

    const long Kb   = (long)K * 2;         // row stride in bytes
    const long r64  = 64 * Kb;
    const long r128 = 128 * Kb;
    const char* gA0 = (const char*)A  + (long)(bm0 + s_row) * Kb + s_colb;
    const char* gB0 = (const char*)Bm + (long)(bn0 + s_row) * Kb + s_colb;

    auto stageH = [&](int buf, int h, long kb) {
        char* ldst = lds + buf * 65536
                   + (h < 2 ? h * 16384 : 32768 + (h - 2) * 16384) + lds_off;
        const char* g = (h < 2 ? gA0 + h * r128 : gB0 + (h - 2) * r128) + kb;
        __builtin_amdgcn_global_load_lds(AS1(g),       AS3(ldst),        16, 0, 0);
        __builtin_amdgcn_global_load_lds(AS1(g + r64), AS3(ldst + 8192), 16, 0, 0);
    };

    // ---- ds_read addressing (swizzled column), per-buffer address registers ----
    const int swzk  = (lrow & 7) << 4;
    const int colK0 = (kgrp * 16) ^ swzk;            // kk=0
    const int colK1 = (kgrp * 16 + 64) ^ swzk;       // kk=1
    const uint32_t ldsbase = (uint32_t)(uintptr_t)AS3(lds);
    const uint32_t aA00 = ldsbase + (wr * 128 + lrow) * 128 + colK0;
    const uint32_t aA01 = ldsbase + (wr * 128 + lrow) * 128 + colK1;
    const uint32_t aB00 = ldsbase + 32768 + (wc * 64 + lrow) * 128 + colK0;
    const uint32_t aB01 = ldsbase + 32768 + (wc * 64 + lrow) * 128 + colK1;
    const uint32_t aA10 = aA00 + 65536, aA11 = aA01 + 65536;
    const uint32_t aB10 = aB00 + 65536, aB11 = aB01 + 65536;

    facc acc[8][4];
    #pragma unroll
    for (int m = 0; m < 8; ++m)
        #pragma unroll
        for (int n = 0; n < 4; ++n)
            acc[m][n] = facc{0.f, 0.f, 0.f, 0.f};

    const int NT = K / BK;   // 16 or 64 (even)

    bfrag aF[4][2];          // A-lo then A-hi (time-shared)
    bfrag bHi[2][2];         // B-hi of current tile
    bfrag bLoE[2][2];        // B-lo, even tiles
    bfrag bLoO[2][2];        // B-lo, odd tiles

    auto rdQ0 = [&](bfrag (&bLo)[2][2], uint32_t A0, uint32_t A1,
                    uint32_t B0, uint32_t B1) {
        DSR(bLo[0][0], B0, 0);    DSR(bLo[0][1], B1, 0);
        DSR(bLo[1][0], B0, 2048); DSR(bLo[1][1], B1, 2048);
        #pragma unroll
        for (int m = 0; m < 4; ++m) {
            DSR(aF[m][0], A0, m * 2048);
            DSR(aF[m][1], A1, m * 2048);
        }
    };

    // ---- prologue: stage tile0 (H0-H3) + tile1 (H0,H1); preload Q0 frags ----
    stageH(0, 0, 0); stageH(0, 1, 0); stageH(0, 2, 0); stageH(0, 3, 0);
    stageH(1, 0, 128); stageH(1, 1, 128);
    asm volatile("s_waitcnt vmcnt(4)" ::: "memory");
    __builtin_amdgcn_s_barrier();
    rdQ0(bLoE, aA00, aA01, aB00, aB01);

    auto ktile = [&](int t, int curbuf,
                     uint32_t A0c, uint32_t A1c, uint32_t B0c, uint32_t B1c,
                     uint32_t A0n, uint32_t A1n, uint32_t B0n, uint32_t B1n,
                     bfrag (&bLoC)[2][2], bfrag (&bLoN)[2][2]) {
        const long k1b = (long)(t + 1) * 128;
        const long k2b = (long)(t + 2) * 128;
        const int  nb  = curbuf ^ 1;

        // ===== P0: Q0 = Alo x Blo  (12 outstanding: bLo4 + aLo8) =====
        if (t + 1 < NT) stageH(nb, 2, k1b);
        __builtin_amdgcn_s_barrier();
        __builtin_amdgcn_s_setprio(1);
        LGKM(6);
        acc[0][0] = MFMA_BF16(aF[0][0], bLoC[0][0], acc[0][0], 0, 0, 0);
        acc[0][0] = MFMA_BF16(aF[0][1], bLoC[0][1], acc[0][0], 0, 0, 0);
        acc[0][1] = MFMA_BF16(aF[0][0], bLoC[1][0], acc[0][1], 0, 0, 0);
        acc[0][1] = MFMA_BF16(aF[0][1], bLoC[1][1], acc[0][1], 0, 0, 0);
        LGKM(4);
        acc[1][0] = MFMA_BF16(aF[1][0], bLoC[0][0], acc[1][0], 0, 0, 0);
        acc[1][0] = MFMA_BF16(aF[1][1], bLoC[0][1], acc[1][0], 0, 0, 0);
        acc[1][1] = MFMA_BF16(aF[1][0], bLoC[1][0], acc[1][1], 0, 0, 0);
        acc[1][1] = MFMA_BF16(aF[1][1], bLoC[1][1], acc[1][1], 0, 0, 0);
        LGKM(2);
        acc[2][0] = MFMA_BF16(aF[2][0], bLoC[0][0], acc[2][0], 0, 0, 0);
        acc[2][0] = MFMA_BF16(aF[2][1], bLoC[0][1], acc[2][0], 0, 0, 0);
        acc[2][1] = MFMA_BF16(aF[2][0], bLoC[1][0], acc[2][1], 0, 0, 0);
        acc[2][1] = MFMA_BF16(aF[2][1], bLoC[1][1], acc[2][1], 0, 0, 0);
        LGKM(0);
        acc[3][0] = MFMA_BF16(aF[3][0], bLoC[0][0], acc[3][0], 0, 0, 0);
        acc[3][0] = MFMA_BF16(aF[3][1], bLoC[0][1], acc[3][0], 0, 0, 0);
        acc[3][1] = MFMA_BF16(aF[3][0], bLoC[1][0], acc[3][1], 0, 0, 0);
        acc[3][1] = MFMA_BF16(aF[3][1], bLoC[1][1], acc[3][1], 0, 0, 0);
        __builtin_amdgcn_s_setprio(0);
        DSR(bHi[0][0], B0c, 2 * 2048); DSR(bHi[0][1], B1c, 2 * 2048);
        DSR(bHi[1][0], B0c, 3 * 2048); DSR(bHi[1][1], B1c, 3 * 2048);
        __builtin_amdgcn_s_barrier();

        // ===== P1: Q1 = Alo x Bhi  (4 outstanding: bHi) =====
        if (t + 1 < NT) stageH(nb, 3, k1b);
        __builtin_amdgcn_s_barrier();
        __builtin_amdgcn_s_setprio(1);
        LGKM(2);
        #pragma unroll
        for (int m = 0; m < 4; ++m) {
            acc[m][2] = MFMA_BF16(aF[m][0], bHi[0][0], acc[m][2], 0, 0, 0);
            acc[m][2] = MFMA_BF16(aF[m][1], bHi[0][1], acc[m][2], 0, 0, 0);
        }
        LGKM(0);
        #pragma unroll
        for (int m = 0; m < 4; ++m) {
            acc[m][3] = MFMA_BF16(aF[m][0], bHi[1][0], acc[m][3], 0, 0, 0);
            acc[m][3] = MFMA_BF16(aF[m][1], bHi[1][1], acc[m][3], 0, 0, 0);
        }
        __builtin_amdgcn_s_setprio(0);
        #pragma unroll
        for (int m = 0; m < 4; ++m) {
            DSR(aF[m][0], A0c, (4 + m) * 2048);
            DSR(aF[m][1], A1c, (4 + m) * 2048);
        }
        __builtin_amdgcn_s_barrier();

        // ===== P2: Q2 = Ahi x Bhi  (8 outstanding: aHi) =====
        if (t + 2 < NT) stageH(curbuf, 0, k2b);
        __builtin_amdgcn_s_barrier();
        __builtin_amdgcn_s_setprio(1);
        LGKM(6);
        acc[4][2] = MFMA_BF16(aF[0][0], bHi[0][0], acc[4][2], 0, 0, 0);
        acc[4][2] = MFMA_BF16(aF[0][1], bHi[0][1], acc[4][2], 0, 0, 0);
        acc[4][3] = MFMA_BF16(aF[0][0], bHi[1][0], acc[4][3], 0, 0, 0);
        acc[4][3] = MFMA_BF16(aF[0][1], bHi[1][1], acc[4][3], 0, 0, 0);
        LGKM(4);
        acc[5][2] = MFMA_BF16(aF[1][0], bHi[0][0], acc[5][2], 0, 0, 0);
        acc[5][2] = MFMA_BF16(aF[1][1], bHi[0][1], acc[5][2], 0, 0, 0);
        acc[5][3] = MFMA_BF16(aF[1][0], bHi[1][0], acc[5][3], 0, 0, 0);
        acc[5][3] = MFMA_BF16(aF[1][1], bHi[1][1], acc[5][3], 0, 0, 0);
        LGKM(2);
        acc[6][2] = MFMA_BF16(aF[2][0], bHi[0][0], acc[6][2], 0, 0, 0);
        acc[6][2] = MFMA_BF16(aF[2][1], bHi[0][1], acc[6][2], 0, 0, 0);
        acc[6][3] = MFMA_BF16(aF[2][0], bHi[1][0], acc[6][3], 0, 0, 0);
        acc[6][3] = MFMA_BF16(aF[2][1], bHi[1][1], acc[6][3], 0, 0, 0);
        LGKM(0);
        acc[7][2] = MFMA_BF16(aF[3][0], bHi[0][0], acc[7][2], 0, 0, 0);
        acc[7][2] = MFMA_BF16(aF[3][1], bHi[0][1], acc[7][2], 0, 0, 0);
        acc[7][3] = MFMA_BF16(aF[3][0], bHi[1][0], acc[7][3], 0, 0, 0);
        acc[7][3] = MFMA_BF16(aF[3][1], bHi[1][1], acc[7][3], 0, 0, 0);
        __builtin_amdgcn_s_setprio(0);
        __builtin_amdgcn_s_barrier();

        // ===== P3: Q3 = Ahi x Blo  (0 outstanding: no lgkm waits) =====
        if (t + 2 < NT) {
            stageH(curbuf, 1, k2b);
            asm volatile("s_waitcnt vmcnt(4)" ::: "memory");
        } else if (t + 1 < NT) {
            asm volatile("s_waitcnt vmcnt(0)" ::: "memory");
        }
        __builtin_amdgcn_s_barrier();
        __builtin_amdgcn_s_setprio(1);
        #pragma unroll
        for (int m = 0; m < 4; ++m) {
            acc[4 + m][0] = MFMA_BF16(aF[m][0], bLoC[0][0], acc[4 + m][0], 0, 0, 0);
            acc[4 + m][0] = MFMA_BF16(aF[m][1], bLoC[0][1], acc[4 + m][0], 0, 0, 0);
            acc[4 + m][1] = MFMA_BF16(aF[m][0], bLoC[1][0], acc[4 + m][1], 0, 0, 0);
            acc[4 + m][1] = MFMA_BF16(aF[m][1], bLoC[1][1], acc[4 + m][1], 0, 0, 0);
        }
        __builtin_amdgcn_s_setprio(0);
        if (t + 1 < NT) rdQ0(bLoN, A0n, A1n, B0n, B1n);
        __builtin_amdgcn_s_barrier();
    };

    for (int t = 0; t < NT; t += 2) {
        ktile(t,     0, aA00, aA01, aB00, aB01, aA10, aA11, aB10, aB11, bLoE, bLoO);
        ktile(t + 1, 1, aA10, aA11, aB10, aB11, aA00, aA01, aB00, aB01, bLoO, bLoE);
    }

    // ---------------- epilogue ----------------
    if constexpr (EPI == 2) {
        float* Cf = reinterpret_cast<float*>(Cout);
        float b2c[4][R_];
        #pragma unroll
        for (int n = 0; n < 4; ++n) {
            const int col = bn0 + wc * 64 + n * 16 + lrow;
            #pragma unroll
            for (int r = 0; r < R_; ++r) b2c[n][r] = b2v[r * N + col];
        }
        #pragma unroll
        for (int m = 0; m < 8; ++m) {
            #pragma unroll
            for (int j = 0; j < 4; ++j) {
                const int row = bm0 + wr * 128 + m * 16 + kgrp * 4 + j;
                const float* g = gate + (long)(gate_row0 + row) * R_;
                float gv[R_];
                #pragma unroll
                for (int r = 0; r < R_; ++r) gv[r] = g[r];
                #pragma unroll
                for (int n = 0; n < 4; ++n) {
                    const int col = bn0 + wc * 64 + n * 16 + lrow;
                    float sv = acc[m][n][j];
                    #pragma unroll
                    for (int r = 0; r < R_; ++r) sv += gv[r] * b2c[n][r];
                    Cf[(long)row * N + col] = sv;
                }
            }
        }
    } else {
        bf16* Cb = reinterpret_cast<bf16*>(Cout);
        float bcol[4];
        #pragma unroll
        for (int n = 0; n < 4; ++n) {
            if constexpr (EPI == 3) bcol[n] = 0.f;
            else bcol[n] = bias[bn0 + wc * 64 + n * 16 + lrow];
        }
        #pragma unroll
        for (int m = 0; m < 8; ++m) {
            #pragma unroll
            for (int j = 0; j < 4; ++j) {
                const int row = bm0 + wr * 128 + m * 16 + kgrp * 4 + j;
                float gv[4];
                if constexpr (EPI == 1) {
                    #pragma unroll
                    for (int n = 0; n < 4; ++n) {
                        const int col = bn0 + wc * 64 + n * 16 + lrow;
                        gv[n] = gate[(long)(gate_row0 + row) * R_ + (col >> 9)];
                    }
                }
                #pragma unroll
                for (int n = 0; n < 4; ++n) {
                    const int col = bn0 + wc * 64 + n * 16 + lrow;
                    float v = acc[m][n][j] + bcol[n];
                    if constexpr (EPI == 1) v = fmaxf(v, 0.f) * gv[n];
                    Cb[(long)row * N + col] = __float2bfloat16(v);
                }
            }
        }
    }
}

extern "C" void kernel_launch(void* const* d_in, const int* in_sizes, int n_in,
                              void* d_out, int out_size, void* d_ws, size_t ws_size,
                              hipStream_t stream)
{
    const float* x   = (const float*)d_in[0];
    const float* ipw = (const float*)d_in[1];
    const float* ipb = (const float*)d_in[2];
    const float* opw = (const float*)d_in[3];
    const float* opb = (const float*)d_in[4];
    const float* W1  = (const float*)d_in[5];
    const float* b1  = (const float*)d_in[6];
    const float* W2  = (const float*)d_in[7];
    const float* b2  = (const float*)d_in[8];
    const float* Wg  = (const float*)d_in[9];
    const float* bg  = (const float*)d_in[10];
    float* out = (float*)d_out;

    const float* Wv_f = ipw + (size_t)2 * D_ * D_;   // (1024,1024) [j][d]
    const float* bv_f = ipb + 2 * D_;

    char* ws = (char*)d_ws;
    size_t off = 0;
    auto alloc = [&](size_t bytes) -> void* {
        void* p = ws + off;
        off += (bytes + 255) & ~(size_t)255;
        return p;
    };

    bf16* xb   = (bf16*)alloc((size_t)B_ * D_ * 2);     // x in bf16
    bf16* ab   = (bf16*)alloc((size_t)B_ * D_ * 2);     // attended
    bf16* Wob  = (bf16*)alloc((size_t)D_ * D_ * 2);     // Wout bf16
    bf16* WvT  = (bf16*)alloc((size_t)D_ * D_ * 2);     // Wv^T bf16
    bf16* Weff = (bf16*)alloc((size_t)D_ * D_ * 2);     // Wout@Wv bf16
    float* beff = (float*)alloc((size_t)D_ * 4);
    bf16* W1b  = (bf16*)alloc((size_t)RH_ * D_ * 2);
    bf16* W2b  = (bf16*)alloc((size_t)DOUT_ * RH_ * 2);
    float* gate = (float*)alloc((size_t)B_ * R_ * 4);

    // h' chunk buffer: largest M-chunk that fits the workspace (multiple of 256)
    int mc = B_;
    while (off + (size_t)mc * RH_ * 2 > ws_size && mc > 1024) mc >>= 1;
    bf16* hb = (bf16*)alloc((size_t)mc * RH_ * 2);

    // ---- conversions / precompute ----
    k_cvt<<<(B_ * D_) / 1024, 256, 0, stream>>>(x, xb, (long)B_ * D_);
    k_cvt<<<(D_ * D_) / 1024, 256, 0, stream>>>(opw, Wob, (long)D_ * D_);
    k_cvt_wvT<<<dim3(16, 16), 256, 0, stream>>>(Wv_f, WvT);
    k_cvt<<<(RH_ * D_) / 1024, 256, 0, stream>>>(W1, W1b, (long)RH_ * D_);
    k_cvt_w2<<<R_ * DOUT_, 128, 0, stream>>>(W2, W2b);
    k_beff<<<D_, 256, 0, stream>>>(opw, bv_f, opb, beff);

    // ---- gate (reads fp32 x directly) ----
    k_gate<<<B_ / 4, 256, 0, stream>>>(x, Wg, bg, gate);

    // ---- Weff = Wout @ Wv  (A=Wob [o][j], B=WvT [d][j]) ----
    k_gemm<3><<<dim3(D_ / BN, D_ / BM), 512, 0, stream>>>(
        Wob, WvT, nullptr, nullptr, nullptr, Weff, D_, D_, D_, 0);

    // ---- G12: attended = x @ Weff^T + beff ----
    k_gemm<0><<<dim3(D_ / BN, B_ / BM), 512, 0, stream>>>(
        xb, Weff, beff, nullptr, nullptr, ab, B_, D_, D_, 0);

    // ---- G3 + G4, chunked over M ----
    for (int m0 = 0; m0 < B_; m0 += mc) {
        // h' = relu(att @ W1cat^T + b1) * gate[:, r]
        k_gemm<1><<<dim3(RH_ / BN, mc / BM), 512, 0, stream>>>(
            ab + (size_t)m0 * D_, W1b, b1, gate, nullptr, hb, mc, RH_, D_, m0);
        // out = h' @ W2cat + gate @ b2
        k_gemm<2><<<dim3(DOUT_ / BN, mc / BM), 512, 0, stream>>>(
            hb, W2b, nullptr, gate, b2, out + (size_t)m0 * DOUT_, mc, DOUT_, RH_, m0);
    }
}

// Round 11
// 377.518 us; speedup vs baseline: 1.0416x; 1.0113x over previous
//
#include <hip/hip_runtime.h>
#include <hip/hip_bf16.h>
#include <cstdint>

typedef __hip_bfloat16 bf16;
typedef __attribute__((ext_vector_type(8))) short bfrag;   // 8 bf16 (4 VGPRs)
typedef __attribute__((ext_vector_type(4))) float facc;    // 4 fp32 acc

#define B_    16384
#define D_    1024
#define DOUT_ 1024
#define R_    8
#define DH_   512
#define RH_   4096

#define BM 256
#define BN 256
#define BK 64

#define NXCD 8
#define KSPLIT 4

#define AS1(p) ((const __attribute__((address_space(1))) void*)(p))
#define AS3(p) ((__attribute__((address_space(3))) void*)(p))

// inline-asm ds_read_b128 (fixed issue order; lgkm counted against these only).
#define DSR(dst, addr, off) \
    asm volatile("ds_read_b128 %0, %1 offset:%c2" : "=v"(dst) : "v"(addr), "i"(off))
#define LGKM(n) do { asm volatile("s_waitcnt lgkmcnt(" #n ")" ::: "memory"); \
                     __builtin_amdgcn_sched_barrier(0); } while (0)

static __device__ __forceinline__ uint32_t pack2bf(float a, float b) {
    unsigned short ua = __builtin_bit_cast(unsigned short, __float2bfloat16(a));
    unsigned short ub = __builtin_bit_cast(unsigned short, __float2bfloat16(b));
    return (uint32_t)ua | ((uint32_t)ub << 16);
}

// ---------------- fp32 -> bf16 conversion (vectorized) ----------------
__global__ void k_cvt(const float* __restrict__ in, bf16* __restrict__ out, long n)
{
    long i = ((long)blockIdx.x * blockDim.x + threadIdx.x) * 4;
    if (i >= n) return;
    float4 v = *reinterpret_cast<const float4*>(in + i);
    uint2 o;
    o.x = pack2bf(v.x, v.y);
    o.y = pack2bf(v.z, v.w);
    *reinterpret_cast<uint2*>(out + i) = o;
}

// ---- W2 (R,DOUT,DH) -> B4 (DOUT, R*DH) with B4[o][r*DH+h] = W2[r][o][h] ----
__global__ void k_cvt_w2(const float* __restrict__ W2, bf16* __restrict__ out)
{
    int b = blockIdx.x;            // 0 .. R_*DOUT_-1
    int r = b >> 10;               // DOUT_ = 1024
    int o = b & 1023;
    const float4* src = reinterpret_cast<const float4*>(W2 + ((long)r * DOUT_ + o) * DH_);
    bf16* dst = out + (long)o * RH_ + r * DH_;
    int t = threadIdx.x;           // 0..127, covers 512 floats
    float4 v = src[t];
    uint2 p;
    p.x = pack2bf(v.x, v.y);
    p.y = pack2bf(v.z, v.w);
    *reinterpret_cast<uint2*>(dst + t * 4) = p;
}

// ---- Wv (1024x1024 f32, [j][d]) -> WvT bf16 [d][j] (LDS-tiled transpose) ----
__global__ __launch_bounds__(256) void k_cvt_wvT(const float* __restrict__ Wv,
                                                 bf16* __restrict__ outT)
{
    __shared__ float tile[64][65];
    const int j0 = blockIdx.y * 64;   // source row block
    const int d0 = blockIdx.x * 64;   // source col block
    const int tx = threadIdx.x & 15;  // 16 x float4 = 64 cols
    const int ty = threadIdx.x >> 4;  // 16 rows per pass
    #pragma unroll
    for (int p = 0; p < 4; ++p) {
        int r = p * 16 + ty;
        float4 v = *reinterpret_cast<const float4*>(&Wv[(long)(j0 + r) * D_ + d0 + tx * 4]);
        tile[r][tx * 4 + 0] = v.x; tile[r][tx * 4 + 1] = v.y;
        tile[r][tx * 4 + 2] = v.z; tile[r][tx * 4 + 3] = v.w;
    }
    __syncthreads();
    #pragma unroll
    for (int p = 0; p < 4; ++p) {
        int r = p * 16 + ty;          // output row (d index)
        uint2 o;
        o.x = pack2bf(tile[tx * 4 + 0][r], tile[tx * 4 + 1][r]);
        o.y = pack2bf(tile[tx * 4 + 2][r], tile[tx * 4 + 3][r]);
        *reinterpret_cast<uint2*>(&outT[(long)(d0 + r) * D_ + j0 + tx * 4]) = o;
    }
}

// ---- beff[o] = sum_d Wout[o,d]*bv[d] + bout[o] ----
__global__ __launch_bounds__(256) void k_beff(const float* __restrict__ Wout,
                                              const float* __restrict__ bv,
                                              const float* __restrict__ bout,
                                              float* __restrict__ beff)
{
    const int o = blockIdx.x;
    float s = 0.f;
    for (int d = threadIdx.x; d < D_; d += 256)
        s += Wout[(long)o * D_ + d] * bv[d];
    #pragma unroll
    for (int off = 32; off > 0; off >>= 1) s += __shfl_xor(s, off);
    __shared__ float ps[4];
    if ((threadIdx.x & 63) == 0) ps[threadIdx.x >> 6] = s;
    __syncthreads();
    if (threadIdx.x == 0)
        beff[o] = ps[0] + ps[1] + ps[2] + ps[3] + bout[o];
}

// ---- reduce KSPLIT f32 partial Weff slices -> bf16 ----
__global__ __launch_bounds__(256) void k_wred(const float* __restrict__ part,
                                              bf16* __restrict__ out)
{
    const long n = (long)D_ * D_;
    long i = ((long)blockIdx.x * 256 + threadIdx.x) * 4;
    float4 a = *reinterpret_cast<const float4*>(part + i);
    float4 b = *reinterpret_cast<const float4*>(part + n + i);
    float4 c = *reinterpret_cast<const float4*>(part + 2 * n + i);
    float4 d = *reinterpret_cast<const float4*>(part + 3 * n + i);
    uint2 o;
    o.x = pack2bf(a.x + b.x + c.x + d.x, a.y + b.y + c.y + d.y);
    o.y = pack2bf(a.z + b.z + c.z + d.z, a.w + b.w + c.w + d.w);
    *reinterpret_cast<uint2*>(out + i) = o;
}

// ---------------- gate = softmax(x @ Wg.T + bg) ----------------
__global__ __launch_bounds__(256) void k_gate(const float* __restrict__ x,
                                              const float* __restrict__ Wg,
                                              const float* __restrict__ bg,
                                              float* __restrict__ gate)
{
    __shared__ float sWg[R_ * D_];
    __shared__ float sbg[R_];
    for (int i = threadIdx.x; i < R_ * D_ / 4; i += 256)
        reinterpret_cast<float4*>(sWg)[i] = reinterpret_cast<const float4*>(Wg)[i];
    if (threadIdx.x < R_) sbg[threadIdx.x] = bg[threadIdx.x];
    __syncthreads();

    const int lane = threadIdx.x & 63;
    const int wave = threadIdx.x >> 6;
    const int row  = blockIdx.x * 4 + wave;     // grid = B_/4

    const float4* xr = reinterpret_cast<const float4*>(x + (long)row * D_);
    float s[R_] = {};
    #pragma unroll
    for (int c = 0; c < 4; ++c) {
        float4 xv = xr[lane + c * 64];
        #pragma unroll
        for (int r = 0; r < R_; ++r) {
            float4 wv = reinterpret_cast<const float4*>(sWg + r * D_)[lane + c * 64];
            s[r] += xv.x * wv.x + xv.y * wv.y + xv.z * wv.z + xv.w * wv.w;
        }
    }
    #pragma unroll
    for (int r = 0; r < R_; ++r) {
        float v = s[r];
        #pragma unroll
        for (int off = 32; off > 0; off >>= 1) v += __shfl_xor(v, off);
        s[r] = v + sbg[r];
    }
    float m = s[0];
    #pragma unroll
    for (int r = 1; r < R_; ++r) m = fmaxf(m, s[r]);
    float den = 0.f;
    #pragma unroll
    for (int r = 0; r < R_; ++r) { s[r] = __expf(s[r] - m); den += s[r]; }
    float inv = 1.f / den;
    if (lane < R_) gate[(long)row * R_ + lane] = s[lane] * inv;
}

// ======== 256x256 8-phase bf16 MFMA GEMM (safe deep t+2 prefetch) ========
// EPI 0: C(bf16) = dot + bias[col]
// EPI 1: C(bf16) = relu(dot + bias[col]) * gate[row][col>>9]
// EPI 2: C(f32)  = dot + sum_r gate[row][r]*b2[r][col]
// EPI 4: C(f32 partial, +z*M*N) = dot    (split-K; blockIdx.z = K-slice)
//
// Region lifetimes (per wave; wr selects H0/H1, wc selects H2/H3):
//   B region of tile t: last reads (bHi) drain at P1's LGKM(0)
//     -> DEAD after end-of-P1 barrier  => stage H2,H3(t+2) at P2 start.
//   A region of tile t: last reads (aF hi) drain at P2's LGKM(0)
//     -> DEAD after end-of-P2 barrier  => stage H0,H1(t+2) at P3 start.
// vmcnt(8) at P3: 16 loads in flight (t+1's 8 + t+2's 8), drains t+1's.
// Every stage is issued after its region's readers COMPLETED (no WAR window —
// r10 staged H0 at P1, racing the end-of-P1 A-hi reads of wr=0 waves: the bug).
#define MFMA_BF16 __builtin_amdgcn_mfma_f32_16x16x32_bf16

template <int EPI>
__global__ __launch_bounds__(512, 2)
void k_gemm(const bf16* __restrict__ A, const bf16* __restrict__ Bm,
            const float* __restrict__ bias, const float* __restrict__ gate,
            const float* __restrict__ b2v, void* __restrict__ Cout,
            int M, int N, int K, int gate_row0, int ldk)
{
    __shared__ char lds[131072];

    const int tid  = threadIdx.x;
    const int lane = tid & 63;
    const int wave = tid >> 6;
    const int wr   = wave >> 2;       // 0..1
    const int wc   = wave & 3;        // 0..3

    // ---- XCD-aware bijective chunked swizzle (m204), row-major decode ----
    const int nwg  = gridDim.x * gridDim.y;
    const int orig = blockIdx.y * gridDim.x + blockIdx.x;
    const int xcd  = orig % NXCD;
    const int q    = nwg / NXCD;
    const int rr   = nwg % NXCD;
    const int wgid = (xcd < rr ? xcd * (q + 1) : rr * (q + 1) + (xcd - rr) * q)
                   + orig / NXCD;
    const int bn0  = (wgid % gridDim.x) * BN;
    const int bm0  = (wgid / gridDim.x) * BM;

    const int lrow = lane & 15;
    const int kgrp = lane >> 4;

    // ---- staging: per-thread pre-swizzled source column, linear LDS dest ----
    const int s_colb  = ((tid & 7) * 16) ^ (((tid >> 3) & 7) << 4);
    const int s_row   = tid >> 3;          // 0..63
    const int lds_off = tid * 16;

    const long Kb   = (long)ldk * 2;       // row stride in bytes
    const long zoff = (long)blockIdx.z * K * 2;
    const long r64  = 64 * Kb;
    const long r128 = 128 * Kb;
    const char* gA0 = (const char*)A  + (long)(bm0 + s_row) * Kb + s_colb + zoff;
    const char* gB0 = (const char*)Bm + (long)(bn0 + s_row) * Kb + s_colb + zoff;

    auto stageH = [&](int buf, int h, long kb) {
        char* ldst = lds + buf * 65536
                   + (h < 2 ? h * 16384 : 32768 + (h - 2) * 16384) + lds_off;
        const char* g = (h < 2 ? gA0 + h * r128 : gB0 + (h - 2) * r128) + kb;
        __builtin_amdgcn_global_load_lds(AS1(g),       AS3(ldst),        16, 0, 0);
        __builtin_amdgcn_global_load_lds(AS1(g + r64), AS3(ldst + 8192), 16, 0, 0);
    };

    // ---- ds_read addressing (swizzled column), per-buffer address registers ----
    const int swzk  = (lrow & 7) << 4;
    const int colK0 = (kgrp * 16) ^ swzk;            // kk=0
    const int colK1 = (kgrp * 16 + 64) ^ swzk;       // kk=1
    const uint32_t ldsbase = (uint32_t)(uintptr_t)AS3(lds);
    const uint32_t aA00 = ldsbase + (wr * 128 + lrow) * 128 + colK0;
    const uint32_t aA01 = ldsbase + (wr * 128 + lrow) * 128 + colK1;
    const uint32_t aB00 = ldsbase + 32768 + (wc * 64 + lrow) * 128 + colK0;
    const uint32_t aB01 = ldsbase + 32768 + (wc * 64 + lrow) * 128 + colK1;
    const uint32_t aA10 = aA00 + 65536, aA11 = aA01 + 65536;
    const uint32_t aB10 = aB00 + 65536, aB11 = aB01 + 65536;

    facc acc[8][4];
    #pragma unroll
    for (int m = 0; m < 8; ++m)
        #pragma unroll
        for (int n = 0; n < 4; ++n)
            acc[m][n] = facc{0.f, 0.f, 0.f, 0.f};

    const int NT = K / BK;   // 4, 16 or 64 (even, >=4)

    bfrag aF[4][2];          // A-lo then A-hi (time-shared)
    bfrag bHi[2][2];         // B-hi of current tile
    bfrag bLoE[2][2];        // B-lo, even tiles
    bfrag bLoO[2][2];        // B-lo, odd tiles

    auto rdQ0 = [&](bfrag (&bLo)[2][2], uint32_t A0, uint32_t A1,
                    uint32_t B0, uint32_t B1) {
        DSR(bLo[0][0], B0, 0);    DSR(bLo[0][1], B1, 0);
        DSR(bLo[1][0], B0, 2048); DSR(bLo[1][1], B1, 2048);
        #pragma unroll
        for (int m = 0; m < 4; ++m) {
            DSR(aF[m][0], A0, m * 2048);
            DSR(aF[m][1], A1, m * 2048);
        }
    };

    // ---- prologue: stage tiles 0 AND 1 fully (16 loads); wait tile0 ----
    stageH(0, 0, 0);   stageH(0, 1, 0);   stageH(0, 2, 0);   stageH(0, 3, 0);
    stageH(1, 0, 128); stageH(1, 1, 128); stageH(1, 2, 128); stageH(1, 3, 128);
    asm volatile("s_waitcnt vmcnt(8)" ::: "memory");
    __builtin_amdgcn_s_barrier();
    rdQ0(bLoE, aA00, aA01, aB00, aB01);

    auto ktile = [&](int t, int curbuf,
                     uint32_t A0c, uint32_t A1c, uint32_t B0c, uint32_t B1c,
                     uint32_t A0n, uint32_t A1n, uint32_t B0n, uint32_t B1n,
                     bfrag (&bLoC)[2][2], bfrag (&bLoN)[2][2]) {
        const long k2b = (long)(t + 2) * 128;

        // ===== P0: Q0 = Alo x Blo  (12 outstanding ds: bLo4 + aLo8) =====
        __builtin_amdgcn_s_barrier();
        __builtin_amdgcn_s_setprio(1);
        LGKM(6);
        acc[0][0] = MFMA_BF16(aF[0][0], bLoC[0][0], acc[0][0], 0, 0, 0);
        acc[0][0] = MFMA_BF16(aF[0][1], bLoC[0][1], acc[0][0], 0, 0, 0);
        acc[0][1] = MFMA_BF16(aF[0][0], bLoC[1][0], acc[0][1], 0, 0, 0);
        acc[0][1] = MFMA_BF16(aF[0][1], bLoC[1][1], acc[0][1], 0, 0, 0);
        LGKM(4);
        acc[1][0] = MFMA_BF16(aF[1][0], bLoC[0][0], acc[1][0], 0, 0, 0);
        acc[1][0] = MFMA_BF16(aF[1][1], bLoC[0][1], acc[1][0], 0, 0, 0);
        acc[1][1] = MFMA_BF16(aF[1][0], bLoC[1][0], acc[1][1], 0, 0, 0);
        acc[1][1] = MFMA_BF16(aF[1][1], bLoC[1][1], acc[1][1], 0, 0, 0);
        LGKM(2);
        acc[2][0] = MFMA_BF16(aF[2][0], bLoC[0][0], acc[2][0], 0, 0, 0);
        acc[2][0] = MFMA_BF16(aF[2][1], bLoC[0][1], acc[2][0], 0, 0, 0);
        acc[2][1] = MFMA_BF16(aF[2][0], bLoC[1][0], acc[2][1], 0, 0, 0);
        acc[2][1] = MFMA_BF16(aF[2][1], bLoC[1][1], acc[2][1], 0, 0, 0);
        LGKM(0);
        acc[3][0] = MFMA_BF16(aF[3][0], bLoC[0][0], acc[3][0], 0, 0, 0);
        acc[3][0] = MFMA_BF16(aF[3][1], bLoC[0][1], acc[3][0], 0, 0, 0);
        acc[3][1] = MFMA_BF16(aF[3][0], bLoC[1][0], acc[3][1], 0, 0, 0);
        acc[3][1] = MFMA_BF16(aF[3][1], bLoC[1][1], acc[3][1], 0, 0, 0);
        __builtin_amdgcn_s_setprio(0);
        DSR(bHi[0][0], B0c, 2 * 2048); DSR(bHi[0][1], B1c, 2 * 2048);
        DSR(bHi[1][0], B0c, 3 * 2048); DSR(bHi[1][1], B1c, 3 * 2048);
        __builtin_amdgcn_s_barrier();

        // ===== P1: Q1 = Alo x Bhi  (4 outstanding: bHi) =====
        __builtin_amdgcn_s_barrier();
        __builtin_amdgcn_s_setprio(1);
        LGKM(2);
        #pragma unroll
        for (int m = 0; m < 4; ++m) {
            acc[m][2] = MFMA_BF16(aF[m][0], bHi[0][0], acc[m][2], 0, 0, 0);
            acc[m][2] = MFMA_BF16(aF[m][1], bHi[0][1], acc[m][2], 0, 0, 0);
        }
        LGKM(0);
        #pragma unroll
        for (int m = 0; m < 4; ++m) {
            acc[m][3] = MFMA_BF16(aF[m][0], bHi[1][0], acc[m][3], 0, 0, 0);
            acc[m][3] = MFMA_BF16(aF[m][1], bHi[1][1], acc[m][3], 0, 0, 0);
        }
        __builtin_amdgcn_s_setprio(0);
        #pragma unroll
        for (int m = 0; m < 4; ++m) {
            DSR(aF[m][0], A0c, (4 + m) * 2048);
            DSR(aF[m][1], A1c, (4 + m) * 2048);
        }
        __builtin_amdgcn_s_barrier();
        // <-- all waves' B reads of tile t COMPLETED (bHi drained at LGKM(0))

        // ===== P2: stage H2,H3(t+2) into curbuf B (dead); Q2 = Ahi x Bhi =====
        if (t + 2 < NT) { stageH(curbuf, 2, k2b); stageH(curbuf, 3, k2b); }
        __builtin_amdgcn_s_barrier();
        __builtin_amdgcn_s_setprio(1);
        LGKM(6);
        acc[4][2] = MFMA_BF16(aF[0][0], bHi[0][0], acc[4][2], 0, 0, 0);
        acc[4][2] = MFMA_BF16(aF[0][1], bHi[0][1], acc[4][2], 0, 0, 0);
        acc[4][3] = MFMA_BF16(aF[0][0], bHi[1][0], acc[4][3], 0, 0, 0);
        acc[4][3] = MFMA_BF16(aF[0][1], bHi[1][1], acc[4][3], 0, 0, 0);
        LGKM(4);
        acc[5][2] = MFMA_BF16(aF[1][0], bHi[0][0], acc[5][2], 0, 0, 0);
        acc[5][2] = MFMA_BF16(aF[1][1], bHi[0][1], acc[5][2], 0, 0, 0);
        acc[5][3] = MFMA_BF16(aF[1][0], bHi[1][0], acc[5][3], 0, 0, 0);
        acc[5][3] = MFMA_BF16(aF[1][1], bHi[1][1], acc[5][3], 0, 0, 0);
        LGKM(2);
        acc[6][2] = MFMA_BF16(aF[2][0], bHi[0][0], acc[6][2], 0, 0, 0);
        acc[6][2] = MFMA_BF16(aF[2][1], bHi[0][1], acc[6][2], 0, 0, 0);
        acc[6][3] = MFMA_BF16(aF[2][0], bHi[1][0], acc[6][3], 0, 0, 0);
        acc[6][3] = MFMA_BF16(aF[2][1], bHi[1][1], acc[6][3], 0, 0, 0);
        LGKM(0);
        acc[7][2] = MFMA_BF16(aF[3][0], bHi[0][0], acc[7][2], 0, 0, 0);
        acc[7][2] = MFMA_BF16(aF[3][1], bHi[0][1], acc[7][2], 0, 0, 0);
        acc[7][3] = MFMA_BF16(aF[3][0], bHi[1][0], acc[7][3], 0, 0, 0);
        acc[7][3] = MFMA_BF16(aF[3][1], bHi[1][1], acc[7][3], 0, 0, 0);
        __builtin_amdgcn_s_setprio(0);
        __builtin_amdgcn_s_barrier();
        // <-- all waves' A reads of tile t COMPLETED (aF hi drained at LGKM(0))

        // ===== P3: stage H0,H1(t+2) into curbuf A (dead); vmcnt(8);
        //           Q3 = Ahi x Blo (registers); rdQ0(t+1) =====
        if (t + 2 < NT) {
            stageH(curbuf, 0, k2b); stageH(curbuf, 1, k2b);
            asm volatile("s_waitcnt vmcnt(8)" ::: "memory");
        } else if (t + 1 < NT) {
            asm volatile("s_waitcnt vmcnt(0)" ::: "memory");
        }
        __builtin_amdgcn_s_barrier();
        __builtin_amdgcn_s_setprio(1);
        #pragma unroll
        for (int m = 0; m < 4; ++m) {
            acc[4 + m][0] = MFMA_BF16(aF[m][0], bLoC[0][0], acc[4 + m][0], 0, 0, 0);
            acc[4 + m][0] = MFMA_BF16(aF[m][1], bLoC[0][1], acc[4 + m][0], 0, 0, 0);
            acc[4 + m][1] = MFMA_BF16(aF[m][0], bLoC[1][0], acc[4 + m][1], 0, 0, 0);
            acc[4 + m][1] = MFMA_BF16(aF[m][1], bLoC[1][1], acc[4 + m][1], 0, 0, 0);
        }
        __builtin_amdgcn_s_setprio(0);
        if (t + 1 < NT) rdQ0(bLoN, A0n, A1n, B0n, B1n);
        __builtin_amdgcn_s_barrier();
    };

    for (int t = 0; t < NT; t += 2) {
        ktile(t,     0, aA00, aA01, aB00, aB01, aA10, aA11, aB10, aB11, bLoE, bLoO);
        ktile(t + 1, 1, aA10, aA11, aB10, aB11, aA00, aA01, aB00, aB01, bLoO, bLoE);
    }

    // ---------------- epilogue ----------------
    if constexpr (EPI == 2) {
        float* Cf = reinterpret_cast<float*>(Cout);
        float b2c[4][R_];
        #pragma unroll
        for (int n = 0; n < 4; ++n) {
            const int col = bn0 + wc * 64 + n * 16 + lrow;
            #pragma unroll
            for (int r = 0; r < R_; ++r) b2c[n][r] = b2v[r * N + col];
        }
        #pragma unroll
        for (int m = 0; m < 8; ++m) {
            #pragma unroll
            for (int j = 0; j < 4; ++j) {
                const int row = bm0 + wr * 128 + m * 16 + kgrp * 4 + j;
                const float* g = gate + (long)(gate_row0 + row) * R_;
                float gv[R_];
                #pragma unroll
                for (int r = 0; r < R_; ++r) gv[r] = g[r];
                #pragma unroll
                for (int n = 0; n < 4; ++n) {
                    const int col = bn0 + wc * 64 + n * 16 + lrow;
                    float sv = acc[m][n][j];
                    #pragma unroll
                    for (int r = 0; r < R_; ++r) sv += gv[r] * b2c[n][r];
                    Cf[(long)row * N + col] = sv;
                }
            }
        }
    } else if constexpr (EPI == 4) {
        float* Cf = reinterpret_cast<float*>(Cout) + (size_t)blockIdx.z * M * N;
        #pragma unroll
        for (int m = 0; m < 8; ++m) {
            #pragma unroll
            for (int j = 0; j < 4; ++j) {
                const int row = bm0 + wr * 128 + m * 16 + kgrp * 4 + j;
                #pragma unroll
                for (int n = 0; n < 4; ++n) {
                    const int col = bn0 + wc * 64 + n * 16 + lrow;
                    Cf[(long)row * N + col] = acc[m][n][j];
                }
            }
        }
    } else {
        bf16* Cb = reinterpret_cast<bf16*>(Cout);
        float bcol[4];
        #pragma unroll
        for (int n = 0; n < 4; ++n) bcol[n] = bias[bn0 + wc * 64 + n * 16 + lrow];
        #pragma unroll
        for (int m = 0; m < 8; ++m) {
            #pragma unroll
            for (int j = 0; j < 4; ++j) {
                const int row = bm0 + wr * 128 + m * 16 + kgrp * 4 + j;
                float gv[4];
                if constexpr (EPI == 1) {
                    #pragma unroll
                    for (int n = 0; n < 4; ++n) {
                        const int col = bn0 + wc * 64 + n * 16 + lrow;
                        gv[n] = gate[(long)(gate_row0 + row) * R_ + (col >> 9)];
                    }
                }
                #pragma unroll
                for (int n = 0; n < 4; ++n) {
                    const int col = bn0 + wc * 64 + n * 16 + lrow;
                    float v = acc[m][n][j] + bcol[n];
                    if constexpr (EPI == 1) v = fmaxf(v, 0.f) * gv[n];
                    Cb[(long)row * N + col] = __float2bfloat16(v);
                }
            }
        }
    }
}

extern "C" void kernel_launch(void* const* d_in, const int* in_sizes, int n_in,
                              void* d_out, int out_size, void* d_ws, size_t ws_size,
                              hipStream_t stream)
{
    const float* x   = (const float*)d_in[0];
    const float* ipw = (const float*)d_in[1];
    const float* ipb = (const float*)d_in[2];
    const float* opw = (const float*)d_in[3];
    const float* opb = (const float*)d_in[4];
    const float* W1  = (const float*)d_in[5];
    const float* b1  = (const float*)d_in[6];
    const float* W2  = (const float*)d_in[7];
    const float* b2  = (const float*)d_in[8];
    const float* Wg  = (const float*)d_in[9];
    const float* bg  = (const float*)d_in[10];
    float* out = (float*)d_out;

    const float* Wv_f = ipw + (size_t)2 * D_ * D_;   // (1024,1024) [j][d]
    const float* bv_f = ipb + 2 * D_;

    char* ws = (char*)d_ws;
    size_t off = 0;
    auto alloc = [&](size_t bytes) -> void* {
        void* p = ws + off;
        off += (bytes + 255) & ~(size_t)255;
        return p;
    };

    bf16* xb   = (bf16*)alloc((size_t)B_ * D_ * 2);     // x in bf16
    bf16* ab   = (bf16*)alloc((size_t)B_ * D_ * 2);     // attended
    bf16* Wob  = (bf16*)alloc((size_t)D_ * D_ * 2);     // Wout bf16
    bf16* WvT  = (bf16*)alloc((size_t)D_ * D_ * 2);     // Wv^T bf16
    bf16* Weff = (bf16*)alloc((size_t)D_ * D_ * 2);     // Wout@Wv bf16
    float* Wpart = (float*)alloc((size_t)KSPLIT * D_ * D_ * 4); // split-K partials
    float* beff = (float*)alloc((size_t)D_ * 4);
    bf16* W1b  = (bf16*)alloc((size_t)RH_ * D_ * 2);
    bf16* W2b  = (bf16*)alloc((size_t)DOUT_ * RH_ * 2);
    float* gate = (float*)alloc((size_t)B_ * R_ * 4);

    // h' chunk buffer: largest M-chunk that fits the workspace (multiple of 256)
    int mc = B_;
    while (off + (size_t)mc * RH_ * 2 > ws_size && mc > 1024) mc >>= 1;
    bf16* hb = (bf16*)alloc((size_t)mc * RH_ * 2);

    // ---- conversions / precompute ----
    k_cvt<<<(B_ * D_) / 1024, 256, 0, stream>>>(x, xb, (long)B_ * D_);
    k_cvt<<<(D_ * D_) / 1024, 256, 0, stream>>>(opw, Wob, (long)D_ * D_);
    k_cvt_wvT<<<dim3(16, 16), 256, 0, stream>>>(Wv_f, WvT);
    k_cvt<<<(RH_ * D_) / 1024, 256, 0, stream>>>(W1, W1b, (long)RH_ * D_);
    k_cvt_w2<<<R_ * DOUT_, 128, 0, stream>>>(W2, W2b);
    k_beff<<<D_, 256, 0, stream>>>(opw, bv_f, opb, beff);

    // ---- gate (reads fp32 x directly) ----
    k_gate<<<B_ / 4, 256, 0, stream>>>(x, Wg, bg, gate);

    // ---- Weff = Wout @ Wv  (split-K over blockIdx.z, then reduce) ----
    k_gemm<4><<<dim3(D_ / BN, D_ / BM, KSPLIT), 512, 0, stream>>>(
        Wob, WvT, nullptr, nullptr, nullptr, Wpart, D_, D_, D_ / KSPLIT, 0, D_);
    k_wred<<<(D_ * D_) / 1024, 256, 0, stream>>>(Wpart, Weff);

    // ---- G12: attended = x @ Weff^T + beff ----
    k_gemm<0><<<dim3(D_ / BN, B_ / BM), 512, 0, stream>>>(
        xb, Weff, beff, nullptr, nullptr, ab, B_, D_, D_, 0, D_);

    // ---- G3 + G4, chunked over M ----
    for (int m0 = 0; m0 < B_; m0 += mc) {
        // h' = relu(att @ W1cat^T + b1) * gate[:, r]
        k_gemm<1><<<dim3(RH_ / BN, mc / BM), 512, 0, stream>>>(
            ab + (size_t)m0 * D_, W1b, b1, gate, nullptr, hb, mc, RH_, D_, m0, D_);
        // out = h' @ W2cat + gate @ b2
        k_gemm<2><<<dim3(DOUT_ / BN, mc / BM), 512, 0, stream>>>(
            hb, W2b, nullptr, gate, b2, out + (size_t)m0 * DOUT_, mc, DOUT_, RH_, m0, RH_);
    }
}